// Round 3
// baseline (143.243 us; speedup 1.0000x reference)
//
#include <hip/hip_runtime.h>
#include <math.h>

#define NB 32
#define NL 2048
#define NH 8
#define NE 64
#define NM 64
#define MRI 128          // 2*NM rows (re stacked over im)

typedef __attribute__((ext_vector_type(8))) __bf16 bf16x8;
typedef __attribute__((ext_vector_type(2))) __bf16 bf16x2;
typedef __attribute__((ext_vector_type(8))) unsigned short us8;
typedef __attribute__((ext_vector_type(4))) float f32x4;
typedef __attribute__((ext_vector_type(16))) float f32x16;

// fp32 -> bf16 RNE (scalar, for table build)
__device__ __forceinline__ unsigned short f2bf(float x) {
  unsigned int u = __builtin_bit_cast(unsigned int, x);
  u = (u + 0x7fffu + ((u >> 16) & 1u)) >> 16;
  return (unsigned short)u;
}

// pack two f32 -> one u32 of 2 bf16 (compiler emits v_cvt_pk_bf16_f32)
__device__ __forceinline__ unsigned int pk2(float lo, float hi) {
  bf16x2 v;
  v[0] = (__bf16)lo;
  v[1] = (__bf16)hi;
  return __builtin_bit_cast(unsigned int, v);
}

// ---------------- tables ----------------
// T  [128][2048] bf16 : row m = cos(2pi*f_m*l/L); row 64+m = -sin(...)
// IT [2048][128] bf16 : col m = scale_m*cos(2pi*m*l'/L); col 64+m = -scale_m*sin(...)
__global__ void tables_k(const int* __restrict__ idx, unsigned short* __restrict__ T,
                         unsigned short* __restrict__ IT) {
  int gid = blockIdx.x * blockDim.x + threadIdx.x;  // 0..262143
  const float w0 = 6.283185307179586f / (float)NL;
  {
    int row = gid >> 11, l = gid & (NL - 1);
    int m = row & 63;
    int f = idx[m];
    float th = (float)((f * l) & (NL - 1)) * w0;
    float s, c;
    sincosf(th, &s, &c);
    T[gid] = f2bf(row < 64 ? c : -s);
  }
  {
    int lp = gid >> 7, k = gid & 127;
    int m = k & 63;
    float th = (float)((m * lp) & (NL - 1)) * w0;
    float s, c;
    sincosf(th, &s, &c);
    float v;
    if (k < 64) v = ((m == 0 ? 1.0f : 2.0f) / (float)NL) * c;
    else        v = (m == 0 ? 0.0f : (-2.0f / (float)NL) * s);
    IT[gid] = f2bf(v);
  }
}

// ---------------- stage A: X = T * q (bf16 MFMA, fp32 acc), barrier-free ----------------
// grid: ((b*8+h)*2+s), 256 thr = 4 waves. Block C tile [128 m_ri][64 e]; wave [64][32].
// A (T) frags direct from global (L2-resident). B (q) wave-private LDS dbuf.
__global__ __launch_bounds__(256) void dft_k(const float* __restrict__ q,
                                             const unsigned short* __restrict__ T,
                                             float* __restrict__ X2) {
  int bid = blockIdx.x;
  int s = bid & 1, h = (bid >> 1) & 7, b = bid >> 4;
  int t = threadIdx.x, lane = t & 63, wid = t >> 6;
  int mh = wid >> 1, eh = wid & 1;
  __shared__ unsigned short Bl[4][2][32 * 64];  // [wave][buf][e 32][l 64] bf16, 4KB each
  const float* qb = q + ((size_t)b * NL * NH + h) * NE + eh * 32;  // q[b][l][h][e]
  int k0b = s * 1024;
  int a_ = lane >> 3;            // l-octet 0..7
  int e4 = (lane & 7) * 4;       // e-quad base within 32
  f32x4 acc[4][2] = {};
  f32x4 st[8];

  auto loads = [&](int c) {
#pragma unroll
    for (int p = 0; p < 8; ++p) {
      int l = a_ * 8 + p;
      st[p] = *(const f32x4*)(qb + (size_t)(k0b + c * 64 + l) * (NH * NE) + e4);
    }
  };
  auto writes = [&](int c) {
    char* base = (char*)&Bl[wid][c & 1][0];
#pragma unroll
    for (int g = 0; g < 2; ++g)
#pragma unroll
      for (int j = 0; j < 4; ++j) {
        int e = e4 + j;
        unsigned int w0 = pk2(st[g * 4 + 0][j], st[g * 4 + 1][j]);
        unsigned int w1 = pk2(st[g * 4 + 2][j], st[g * 4 + 3][j]);
        int off = (e * 128 + (a_ * 2 + g) * 8) ^ ((lane & 7) << 3);
        *(uint2*)(base + off) = make_uint2(w0, w1);
      }
  };
  auto compute = [&](int c) {
    const char* base = (const char*)&Bl[wid][c & 1][0];
#pragma unroll
    for (int ks2 = 0; ks2 < 2; ++ks2) {
      bf16x8 bfr[2];
#pragma unroll
      for (int fn = 0; fn < 2; ++fn) {
        int e = fn * 16 + (lane & 15);
        int sw = ((e >> 2) & 7) << 3;
        int off = e * 128 + ks2 * 64 + (lane >> 4) * 16;
        uint2 lo = *(const uint2*)(base + (off ^ sw));
        uint2 hi = *(const uint2*)(base + ((off + 8) ^ sw));
        uint4 u = make_uint4(lo.x, lo.y, hi.x, hi.y);
        bfr[fn] = __builtin_bit_cast(bf16x8, u);
      }
#pragma unroll
      for (int fm = 0; fm < 4; ++fm) {
        int row = mh * 64 + fm * 16 + (lane & 15);
        const us8* ap = (const us8*)((const char*)T + (size_t)row * (NL * 2) +
                                     (size_t)(k0b + c * 64 + ks2 * 32 + (lane >> 4) * 8) * 2);
        bf16x8 afr = __builtin_bit_cast(bf16x8, *ap);
#pragma unroll
        for (int fn = 0; fn < 2; ++fn)
          acc[fm][fn] = __builtin_amdgcn_mfma_f32_16x16x32_bf16(afr, bfr[fn], acc[fm][fn], 0, 0, 0);
      }
    }
  };

  loads(0);
  writes(0);
  for (int c = 0; c < 16; ++c) {
    if (c + 1 < 16) loads(c + 1);
    compute(c);
    if (c + 1 < 16) writes(c + 1);
  }
  // X2[bid][128][64] fp32 ; 16x16 C frag: col=lane&15, row=(lane>>4)*4+reg
  float* Xo = X2 + (size_t)bid * (MRI * NE);
#pragma unroll
  for (int fm = 0; fm < 4; ++fm)
#pragma unroll
    for (int fn = 0; fn < 2; ++fn)
#pragma unroll
      for (int r4 = 0; r4 < 4; ++r4) {
        int row = mh * 64 + fm * 16 + (lane >> 4) * 4 + r4;
        int col = eh * 32 + fn * 16 + (lane & 15);
        Xo[row * NE + col] = acc[fm][fn][r4];
      }
}

// ---------------- stage B: complex mix, fp32, m-pair blocks ----------------
// grid: h(8) x m-pair(32) = 256 blocks, 512 thr. O[b][h][o][m_ri] bf16.
__global__ __launch_bounds__(512) void mix_k(const float* __restrict__ X2,
                                             const float* __restrict__ wr,
                                             const float* __restrict__ wi,
                                             unsigned short* __restrict__ O) {
  int h = blockIdx.x >> 5;
  int m0 = (blockIdx.x & 31) * 2;
  __shared__ float Ws[2][2][64][64];   // [m'][ri][i][o] f32 (64 KB)
  __shared__ float Xs[2][2][32][66];   // [m'][ri][b][i+pad]  (67.6 KB)
  int t = threadIdx.x;
  // stage W: f32x2 over the m-pair (innermost dim of w)
  for (int rep = 0; rep < 8; ++rep) {
    int id = rep * 512 + t;            // (i,o) over 4096
    int i = id >> 6, o = id & 63;
    size_t off = (((size_t)(h * 64 + i) * 64 + o) * 64 + m0);
    float2 vr = *(const float2*)(wr + off);
    float2 vi_ = *(const float2*)(wi + off);
    Ws[0][0][i][o] = vr.x;  Ws[1][0][i][o] = vr.y;
    Ws[0][1][i][o] = vi_.x; Ws[1][1][i][o] = vi_.y;
  }
  // stage X: rows m0,m0+1 (re) and 64+m0,64+m0+1 (im), sum the 2 K-splits
  for (int rep = 0; rep < 8; ++rep) {
    int id = rep * 512 + t;            // 32b x 2m' x 64i = 4096
    int bb = id >> 7;
    int mp = (id >> 6) & 1, i = id & 63;
    size_t base = ((size_t)(bb * 8 + h) * 2) * (MRI * NE);
    float xr = X2[base + (size_t)(m0 + mp) * NE + i] +
               X2[base + MRI * NE + (size_t)(m0 + mp) * NE + i];
    float xi = X2[base + (size_t)(64 + m0 + mp) * NE + i] +
               X2[base + MRI * NE + (size_t)(64 + m0 + mp) * NE + i];
    Xs[mp][0][bb][i] = xr;
    Xs[mp][1][bb][i] = xi;
  }
  __syncthreads();
  int bb = t >> 4, o0 = (t & 15) * 4;  // thread: 1 b, 4 o, both m'
  float ar[2][4] = {{0.f}}, ai[2][4] = {{0.f}};
  for (int i = 0; i < 64; ++i) {
    f32x4 w0r = *(const f32x4*)&Ws[0][0][i][o0];
    f32x4 w0i = *(const f32x4*)&Ws[0][1][i][o0];
    f32x4 w1r = *(const f32x4*)&Ws[1][0][i][o0];
    f32x4 w1i = *(const f32x4*)&Ws[1][1][i][o0];
    float x0r = Xs[0][0][bb][i], x0i = Xs[0][1][bb][i];
    float x1r = Xs[1][0][bb][i], x1i = Xs[1][1][bb][i];
#pragma unroll
    for (int k = 0; k < 4; ++k) {
      ar[0][k] += x0r * w0r[k] - x0i * w0i[k];
      ai[0][k] += x0r * w0i[k] + x0i * w0r[k];
      ar[1][k] += x1r * w1r[k] - x1i * w1i[k];
      ai[1][k] += x1r * w1i[k] + x1i * w1r[k];
    }
  }
#pragma unroll
  for (int k = 0; k < 4; ++k) {
    size_t ob = (((size_t)bb * 8 + h) * 64 + (o0 + k)) * MRI;
    *(unsigned int*)(O + ob + m0) = pk2(ar[0][k], ar[1][k]);        // re pair
    *(unsigned int*)(O + ob + 64 + m0) = pk2(ai[0][k], ai[1][k]);   // im pair
  }
}

// ---------------- stage C: out = O * IT^T (bf16 MFMA), LDS-free ----------------
// grid: ((b*4+rt)*16+ct) = 2048 blocks, 256 thr; block tile [128 (h,o)][128 l'], K=128
__global__ __launch_bounds__(256) void idft_k(const unsigned short* __restrict__ O,
                                              const unsigned short* __restrict__ IT,
                                              float* __restrict__ out) {
  int bid = blockIdx.x;
  int ct = bid & 15, rt = (bid >> 4) & 3, b = bid >> 6;
  int t = threadIdx.x, lane = t & 63, wid = t >> 6;
  int wr2 = (wid >> 1) * 64, wc = (wid & 1) * 64;
  const unsigned short* Ab = O + ((size_t)b * 512 + rt * 128 + wr2) * MRI;
  const unsigned short* Bb = IT + ((size_t)ct * 128 + wc) * MRI;
  f32x16 acc[2][2] = {};
#pragma unroll 4
  for (int ks = 0; ks < 8; ++ks) {
    bf16x8 af[2], bfv[2];
#pragma unroll
    for (int i2 = 0; i2 < 2; ++i2) {
      int row = i2 * 32 + (lane & 31);
      af[i2] = __builtin_bit_cast(
          bf16x8, *(const us8*)(Ab + (size_t)row * MRI + ks * 16 + (lane >> 5) * 8));
      bfv[i2] = __builtin_bit_cast(
          bf16x8, *(const us8*)(Bb + (size_t)row * MRI + ks * 16 + (lane >> 5) * 8));
    }
#pragma unroll
    for (int i2 = 0; i2 < 2; ++i2)
#pragma unroll
      for (int j2 = 0; j2 < 2; ++j2)
        acc[i2][j2] = __builtin_amdgcn_mfma_f32_32x32x16_bf16(af[i2], bfv[j2], acc[i2][j2], 0, 0, 0);
  }
  // 32x32 C frag: col=lane&31, row=(reg&3)+8*(reg>>2)+4*(lane>>5)
  float* ob = out + ((size_t)b * 512 + rt * 128) * NL + ct * 128;
#pragma unroll
  for (int i2 = 0; i2 < 2; ++i2)
#pragma unroll
    for (int j2 = 0; j2 < 2; ++j2)
#pragma unroll
      for (int rg = 0; rg < 16; ++rg) {
        int row = wr2 + i2 * 32 + ((rg & 3) + 8 * (rg >> 2) + 4 * (lane >> 5));
        int col = wc + j2 * 32 + (lane & 31);
        ob[(size_t)row * NL + col] = acc[i2][j2][rg];
      }
}

extern "C" void kernel_launch(void* const* d_in, const int* in_sizes, int n_in,
                              void* d_out, int out_size, void* d_ws, size_t ws_size,
                              hipStream_t stream) {
  const float* q = (const float*)d_in[0];
  const float* wr = (const float*)d_in[3];
  const float* wi = (const float*)d_in[4];
  const int* idx = (const int*)d_in[5];
  float* out = (float*)d_out;
  char* ws = (char*)d_ws;

  constexpr size_t TBYTES = (size_t)MRI * NL * 2;              // 512 KB each table
  constexpr size_t X2ELEM = (size_t)NB * NH * 2 * MRI * NE;    // 4,194,304 f32
  constexpr size_t OELEM = (size_t)NB * NH * NE * MRI;         // 2,097,152 bf16
  constexpr size_t NEED = 2 * TBYTES + X2ELEM * 4 + OELEM * 2;
  if (ws_size < NEED) return;

  unsigned short* T = (unsigned short*)ws;
  unsigned short* IT = (unsigned short*)(ws + TBYTES);
  float* X2 = (float*)(ws + 2 * TBYTES);
  unsigned short* O = (unsigned short*)(ws + 2 * TBYTES + X2ELEM * 4);

  hipLaunchKernelGGL(tables_k, dim3(1024), dim3(256), 0, stream, idx, T, IT);
  hipLaunchKernelGGL(dft_k, dim3(NB * NH * 2), dim3(256), 0, stream, q, T, X2);
  hipLaunchKernelGGL(mix_k, dim3(256), dim3(512), 0, stream, X2, wr, wi, O);
  hipLaunchKernelGGL(idft_k, dim3(NB * 4 * 16), dim3(256), 0, stream, O, IT, out);
}

// Round 4
// 115.216 us; speedup vs baseline: 1.2433x; 1.2433x over previous
//
#include <hip/hip_runtime.h>
#include <math.h>

#define NB 32
#define NL 2048
#define NH 8
#define NE 64
#define NM 64
#define MRI 128          // 2*NM rows (re stacked over im)
#define KS 2             // K-split for dft grid
#define BKA 64           // K-chunk for dft

typedef __attribute__((ext_vector_type(8))) __bf16 bf16x8;
typedef __attribute__((ext_vector_type(2))) __bf16 bf16x2;
typedef __attribute__((ext_vector_type(8))) unsigned short us8;
typedef __attribute__((ext_vector_type(4))) float f32x4;
typedef __attribute__((ext_vector_type(16))) float f32x16;

// fp32 -> bf16 RNE (scalar, table build)
__device__ __forceinline__ unsigned short f2bf(float x) {
  unsigned int u = __builtin_bit_cast(unsigned int, x);
  u = (u + 0x7fffu + ((u >> 16) & 1u)) >> 16;
  return (unsigned short)u;
}

// pack two f32 -> u32 of 2 bf16 (v_cvt_pk_bf16_f32)
__device__ __forceinline__ unsigned int pk2(float lo, float hi) {
  bf16x2 v;
  v[0] = (__bf16)lo;
  v[1] = (__bf16)hi;
  return __builtin_bit_cast(unsigned int, v);
}

__device__ __forceinline__ void gll16(const void* g, void* l) {
  __builtin_amdgcn_global_load_lds(
      (const __attribute__((address_space(1))) void*)g,
      (__attribute__((address_space(3))) void*)l, 16, 0, 0);
}

// ---------------- tables ----------------
// T  [128][2048] bf16 : row m = cos(2pi*f_m*l/L); row 64+m = -sin(...)
// IT [2048][128] bf16 : col m = scale_m*cos(2pi*m*l'/L); col 64+m = -scale_m*sin(...)
__global__ void tables_k(const int* __restrict__ idx, unsigned short* __restrict__ T,
                         unsigned short* __restrict__ IT) {
  int gid = blockIdx.x * blockDim.x + threadIdx.x;  // 0..262143
  const float w0 = 6.283185307179586f / (float)NL;
  {
    int row = gid >> 11, l = gid & (NL - 1);
    int m = row & 63;
    int f = idx[m];
    float th = (float)((f * l) & (NL - 1)) * w0;
    float s, c;
    sincosf(th, &s, &c);
    T[gid] = f2bf(row < 64 ? c : -s);
  }
  {
    int lp = gid >> 7, k = gid & 127;
    int m = k & 63;
    float th = (float)((m * lp) & (NL - 1)) * w0;
    float s, c;
    sincosf(th, &s, &c);
    float v;
    if (k < 64) v = ((m == 0 ? 1.0f : 2.0f) / (float)NL) * c;
    else        v = (m == 0 ? 0.0f : (-2.0f / (float)NL) * s);
    IT[gid] = f2bf(v);
  }
}

// ---------------- stage A: X = T * q (bf16 MFMA, fp32 acc) ----------------
// grid: (b*8+h)*2+s = 512 blocks; 256 thr = 4 waves; C tile [128 m_ri][64 e], K=1024.
// A (T) via global_load_lds w/ XOR swizzle; B (q) reg-staged into padded-row LDS.
__global__ __launch_bounds__(256) void dft_k(const float* __restrict__ q,
                                             const unsigned short* __restrict__ T,
                                             float* __restrict__ X2) {
  int bid = blockIdx.x;
  int s = bid & 1, h = (bid >> 1) & 7, b = bid >> 4;
  int t = threadIdx.x, lane = t & 63, wid = t >> 6;
  int mh = wid >> 1, eh = wid & 1;
  __shared__ unsigned short Al[2][MRI * BKA];  // [row 128][k 64], rows 128B, XOR (row&7)<<4
  __shared__ unsigned short Bl[2][NE * 72];    // [e 64][l 64 + pad], rows 144B, no XOR
  const float* qb = q + ((size_t)b * NL * NH + h) * NE;  // q[b][l][h][e]
  int k0b = s * (NL / KS);
  int eq = t >> 4;        // e-quad 0..15  -> e = eq*4 + j
  int lq = t & 15;        // l-quad 0..15  -> l = lq*4 + p
  f32x4 acc[4][2] = {};
  f32x4 st[4];

  auto stageA = [&](int bufi, int k0) {
#pragma unroll
    for (int n = 0; n < 4; ++n) {
      int lin = n * 4096 + wid * 1024 + lane * 16;
      int row = lin >> 7;
      int colb = (lin & 127) ^ ((row & 7) << 4);   // pre-swizzled global source
      gll16((const char*)T + (size_t)row * (NL * 2) + (size_t)k0 * 2 + colb,
            (char*)&Al[bufi][0] + n * 4096 + wid * 1024);
    }
  };
  auto loads = [&](int c) {
#pragma unroll
    for (int p = 0; p < 4; ++p)
      st[p] = *(const f32x4*)(qb + (size_t)(k0b + c * 64 + lq * 4 + p) * (NH * NE) + eq * 4);
  };
  auto writes = [&](int bufi) {
    char* base = (char*)&Bl[bufi][0];
#pragma unroll
    for (int j = 0; j < 4; ++j) {
      int e = eq * 4 + j;
      unsigned int w0 = pk2(st[0][j], st[1][j]);
      unsigned int w1 = pk2(st[2][j], st[3][j]);
      *(uint2*)(base + e * 144 + lq * 8) = make_uint2(w0, w1);  // conflict-free
    }
  };
  auto compute = [&](int bufi) {
    const char* ab = (const char*)&Al[bufi][0];
    const char* bb = (const char*)&Bl[bufi][0];
#pragma unroll
    for (int ks2 = 0; ks2 < 2; ++ks2) {
      bf16x8 bfr[2];
#pragma unroll
      for (int fn = 0; fn < 2; ++fn) {
        int e = eh * 32 + fn * 16 + (lane & 15);
        int off = e * 144 + ks2 * 64 + (lane >> 4) * 16;
        bfr[fn] = __builtin_bit_cast(bf16x8, *(const us8*)(bb + off));
      }
#pragma unroll
      for (int fm = 0; fm < 4; ++fm) {
        int row = mh * 64 + fm * 16 + (lane & 15);
        int off = ((row << 7) + (ks2 << 6) + ((lane >> 4) << 4)) ^ ((row & 7) << 4);
        bf16x8 afr = __builtin_bit_cast(bf16x8, *(const us8*)(ab + off));
#pragma unroll
        for (int fn = 0; fn < 2; ++fn)
          acc[fm][fn] = __builtin_amdgcn_mfma_f32_16x16x32_bf16(afr, bfr[fn], acc[fm][fn], 0, 0, 0);
      }
    }
  };

  stageA(0, k0b);
  loads(0);
  writes(0);
  __syncthreads();
  const int NCH = (NL / KS) / BKA;  // 16
  for (int c = 0; c < NCH; ++c) {
    int cur = c & 1;
    bool more = (c + 1) < NCH;
    if (more) {
      stageA(cur ^ 1, k0b + (c + 1) * BKA);
      loads(c + 1);
    }
    compute(cur);
    if (more) writes(cur ^ 1);
    __syncthreads();
  }
  // X2[bid][128][64] fp32 ; 16x16 C frag: col=lane&15, row=(lane>>4)*4+reg
  float* Xo = X2 + (size_t)bid * (MRI * NE);
#pragma unroll
  for (int fm = 0; fm < 4; ++fm)
#pragma unroll
    for (int fn = 0; fn < 2; ++fn)
#pragma unroll
      for (int r4 = 0; r4 < 4; ++r4) {
        int row = mh * 64 + fm * 16 + (lane >> 4) * 4 + r4;
        int col = eh * 32 + fn * 16 + (lane & 15);
        Xo[row * NE + col] = acc[fm][fn][r4];
      }
}

// ---------------- stage B: complex mix, fp32, m-pair blocks, XCD-swizzled ----------------
// 256 blocks, 256 thr. Logical block = (h, m-pair); XCD k owns h=k -> W[h] L2-resident.
__global__ __launch_bounds__(256) void mix_k(const float* __restrict__ X2,
                                             const float* __restrict__ wr,
                                             const float* __restrict__ wi,
                                             unsigned short* __restrict__ O) {
  int logical = (blockIdx.x & 7) * 32 + (blockIdx.x >> 3);  // bijective (256 % 8 == 0)
  int h = logical >> 5;
  int m0 = (logical & 31) * 2;
  __shared__ float Ws[2][2][64][64];   // [m'][ri][i][o] f32, 64 KB
  __shared__ float Xs[2][2][32][68];   // [m'][ri][b][i(+pad)] f32, 34.8 KB
  int t = threadIdx.x;
  // stage W: float2 over the m-pair (m innermost in w)
  for (int rep = 0; rep < 16; ++rep) {
    int id = rep * 256 + t;            // (i,o) over 4096
    int i = id >> 6, o = id & 63;
    size_t off = (((size_t)(h * 64 + i) * 64 + o) * 64 + m0);
    float2 vr = *(const float2*)(wr + off);
    float2 vi_ = *(const float2*)(wi + off);
    Ws[0][0][i][o] = vr.x;  Ws[1][0][i][o] = vr.y;
    Ws[0][1][i][o] = vi_.x; Ws[1][1][i][o] = vi_.y;
  }
  // stage X: f32x4 over i, summing the 2 K-splits
  for (int rep = 0; rep < 4; ++rep) {
    int id = rep * 256 + t;            // 2 mp x 32 b x 16 iq = 1024
    int mp = id >> 9, bb = (id >> 4) & 31, iq = id & 15;
    size_t base = ((size_t)(bb * 8 + h) * 2) * (MRI * NE);
    f32x4 xr = *(const f32x4*)(X2 + base + (size_t)(m0 + mp) * NE + iq * 4);
    f32x4 xr2 = *(const f32x4*)(X2 + base + MRI * NE + (size_t)(m0 + mp) * NE + iq * 4);
    f32x4 xi = *(const f32x4*)(X2 + base + (size_t)(64 + m0 + mp) * NE + iq * 4);
    f32x4 xi2 = *(const f32x4*)(X2 + base + MRI * NE + (size_t)(64 + m0 + mp) * NE + iq * 4);
    *(f32x4*)&Xs[mp][0][bb][iq * 4] = xr + xr2;
    *(f32x4*)&Xs[mp][1][bb][iq * 4] = xi + xi2;
  }
  __syncthreads();
  int o0 = (t & 15) * 4, b0 = (t >> 4) * 2;  // thread: 2 b, 4 o, both m'
  float ar[2][2][4] = {{{0.f}}}, ai[2][2][4] = {{{0.f}}};
  for (int i = 0; i < 64; ++i) {
#pragma unroll
    for (int mp = 0; mp < 2; ++mp) {
      f32x4 wvr = *(const f32x4*)&Ws[mp][0][i][o0];
      f32x4 wvi = *(const f32x4*)&Ws[mp][1][i][o0];
#pragma unroll
      for (int bj = 0; bj < 2; ++bj) {
        float xr = Xs[mp][0][b0 + bj][i], xi = Xs[mp][1][b0 + bj][i];
#pragma unroll
        for (int k = 0; k < 4; ++k) {
          ar[mp][bj][k] += xr * wvr[k] - xi * wvi[k];
          ai[mp][bj][k] += xr * wvi[k] + xi * wvr[k];
        }
      }
    }
  }
#pragma unroll
  for (int bj = 0; bj < 2; ++bj)
#pragma unroll
    for (int k = 0; k < 4; ++k) {
      size_t ob = (((size_t)(b0 + bj) * 8 + h) * 64 + (o0 + k)) * MRI;
      *(unsigned int*)(O + ob + m0) = pk2(ar[0][bj][k], ar[1][bj][k]);       // re pair
      *(unsigned int*)(O + ob + 64 + m0) = pk2(ai[0][bj][k], ai[1][bj][k]);  // im pair
    }
}

// ---------------- stage C: out = O * IT^T (bf16 MFMA, fp32 acc) ----------------
// grid: b(32) x rowtile(4) x coltile(16); block tile [128 (h,o)][128 l'], K=128
__global__ __launch_bounds__(256) void idft_k(const unsigned short* __restrict__ O,
                                              const unsigned short* __restrict__ IT,
                                              float* __restrict__ out) {
  int bid = blockIdx.x;
  int ct = bid & 15, rt = (bid >> 4) & 3, b = bid >> 6;
  int t = threadIdx.x, lane = t & 63, wid = t >> 6;
  __shared__ unsigned short Als[128 * 128];  // O rows 256B, swizzled
  __shared__ unsigned short Bls[128 * 128];  // ITt rows 256B, swizzled
  const unsigned short* Og = O + ((size_t)b * 512 + rt * 128) * MRI;
  const unsigned short* Ig = IT + (size_t)ct * 128 * MRI;
#pragma unroll
  for (int n = 0; n < 8; ++n) {
    int lin = n * 4096 + wid * 1024 + lane * 16;
    int row = lin >> 8;
    int colb = (lin & 255) ^ ((row & 7) << 4);
    gll16((const char*)Og + (size_t)row * 256 + colb, (char*)Als + n * 4096 + wid * 1024);
  }
#pragma unroll
  for (int n = 0; n < 8; ++n) {
    int lin = n * 4096 + wid * 1024 + lane * 16;
    int row = lin >> 8;
    int colb = (lin & 255) ^ ((row & 7) << 4);
    gll16((const char*)Ig + (size_t)row * 256 + colb, (char*)Bls + n * 4096 + wid * 1024);
  }
  __syncthreads();
  int wr2 = (wid >> 1) * 64, wc = (wid & 1) * 64;
  f32x16 acc[2][2] = {};
#pragma unroll
  for (int ksp = 0; ksp < 8; ++ksp) {
    bf16x8 af[2], bfv[2];
#pragma unroll
    for (int i2 = 0; i2 < 2; ++i2) {
      int row = wr2 + i2 * 32 + (lane & 31);
      int off = ((row << 8) + (ksp << 5) + ((lane >> 5) << 4)) ^ ((row & 7) << 4);
      af[i2] = __builtin_bit_cast(bf16x8, *(const us8*)((const char*)Als + off));
      int nr = wc + i2 * 32 + (lane & 31);
      int off2 = ((nr << 8) + (ksp << 5) + ((lane >> 5) << 4)) ^ ((nr & 7) << 4);
      bfv[i2] = __builtin_bit_cast(bf16x8, *(const us8*)((const char*)Bls + off2));
    }
#pragma unroll
    for (int i2 = 0; i2 < 2; ++i2)
#pragma unroll
      for (int j2 = 0; j2 < 2; ++j2)
        acc[i2][j2] = __builtin_amdgcn_mfma_f32_32x32x16_bf16(af[i2], bfv[j2], acc[i2][j2], 0, 0, 0);
  }
  // 32x32 C frag: col=lane&31, row=(reg&3)+8*(reg>>2)+4*(lane>>5)
  float* ob = out + ((size_t)b * 512 + rt * 128) * NL + ct * 128;
#pragma unroll
  for (int i2 = 0; i2 < 2; ++i2)
#pragma unroll
    for (int j2 = 0; j2 < 2; ++j2)
#pragma unroll
      for (int rg = 0; rg < 16; ++rg) {
        int row = wr2 + i2 * 32 + ((rg & 3) + 8 * (rg >> 2) + 4 * (lane >> 5));
        int col = wc + j2 * 32 + (lane & 31);
        ob[(size_t)row * NL + col] = acc[i2][j2][rg];
      }
}

extern "C" void kernel_launch(void* const* d_in, const int* in_sizes, int n_in,
                              void* d_out, int out_size, void* d_ws, size_t ws_size,
                              hipStream_t stream) {
  const float* q = (const float*)d_in[0];
  const float* wr = (const float*)d_in[3];
  const float* wi = (const float*)d_in[4];
  const int* idx = (const int*)d_in[5];
  float* out = (float*)d_out;
  char* ws = (char*)d_ws;

  constexpr size_t TBYTES = (size_t)MRI * NL * 2;              // 512 KB each table
  constexpr size_t X2ELEM = (size_t)NB * NH * KS * MRI * NE;   // 4,194,304 f32
  constexpr size_t OELEM = (size_t)NB * NH * NE * MRI;         // 2,097,152 bf16
  constexpr size_t NEED = 2 * TBYTES + X2ELEM * 4 + OELEM * 2;
  if (ws_size < NEED) return;

  unsigned short* T = (unsigned short*)ws;
  unsigned short* IT = (unsigned short*)(ws + TBYTES);
  float* X2 = (float*)(ws + 2 * TBYTES);
  unsigned short* O = (unsigned short*)(ws + 2 * TBYTES + X2ELEM * 4);

  hipLaunchKernelGGL(tables_k, dim3(1024), dim3(256), 0, stream, idx, T, IT);
  hipLaunchKernelGGL(dft_k, dim3(NB * NH * KS), dim3(256), 0, stream, q, T, X2);
  hipLaunchKernelGGL(mix_k, dim3(256), dim3(256), 0, stream, X2, wr, wi, O);
  hipLaunchKernelGGL(idft_k, dim3(NB * 4 * 16), dim3(256), 0, stream, O, IT, out);
}